// Round 1
// baseline (1587.716 us; speedup 1.0000x reference)
//
#include <hip/hip_runtime.h>
#include <hip/hip_bf16.h>

#define N_NODES 262144
#define DIM     1024
#define G_SEG   1024
#define NATTR   17
#define EPS_BN  1e-5f

__device__ __forceinline__ float4 f4zero() { float4 r; r.x=0.f;r.y=0.f;r.z=0.f;r.w=0.f; return r; }
__device__ __forceinline__ float4 f4add(float4 a, float4 b) {
    float4 r; r.x=a.x+b.x; r.y=a.y+b.y; r.z=a.z+b.z; r.w=a.w+b.w; return r;
}
__device__ __forceinline__ float4 f4fma(float s, float4 a, float4 acc) {
    float4 r; r.x=fmaf(s,a.x,acc.x); r.y=fmaf(s,a.y,acc.y); r.z=fmaf(s,a.z,acc.z); r.w=fmaf(s,a.w,acc.w); return r;
}

// ---------------- k0: segment boundaries via binary search (batch is sorted) ----------------
__global__ void k_seg_bounds(const int* __restrict__ batch, int* __restrict__ seg_start) {
    int g = blockIdx.x * blockDim.x + threadIdx.x;
    if (g > G_SEG) return;
    int lo = 0, hi = N_NODES;
    while (lo < hi) { int mid = (lo + hi) >> 1; if (batch[mid] < g) lo = mid + 1; else hi = mid; }
    seg_start[g] = lo;
}

// ---------------- k1: per-segment attr sums / type counts / pin histogram ----------------
// segdata layout per segment (stride 64): [0..16]=sum attr (type0), [17..33]=sum attr (type1),
// [34..50]=pin index histogram, [51]=cnt0, [52]=cnt1
__launch_bounds__(256)
__global__ void k_attr_sums(const float* __restrict__ attr, const int* __restrict__ ntype,
                            const int* __restrict__ seg_start, float* __restrict__ segdata) {
    int g = blockIdx.x;
    int s = seg_start[g], e = seg_start[g + 1];
    float a0[NATTR], a1[NATTR], pc[NATTR];
#pragma unroll
    for (int k = 0; k < NATTR; ++k) { a0[k]=0.f; a1[k]=0.f; pc[k]=0.f; }
    float c0 = 0.f, c1 = 0.f;
    for (int i = s + threadIdx.x; i < e; i += 256) {
        int t = ntype[i];
        const float* ap = attr + (size_t)i * NATTR;
        float a[NATTR];
#pragma unroll
        for (int k = 0; k < NATTR; ++k) a[k] = ap[k];
        if (t == 0) {
#pragma unroll
            for (int k = 0; k < NATTR; ++k) a0[k] += a[k];
            c0 += 1.f;
        } else if (t == 1) {
#pragma unroll
            for (int k = 0; k < NATTR; ++k) a1[k] += a[k];
            c1 += 1.f;
        } else if (t == 2) {
            int idx = (int)a[0];
            idx = idx < 0 ? 0 : (idx > NATTR - 1 ? NATTR - 1 : idx);
#pragma unroll
            for (int k = 0; k < NATTR; ++k) pc[k] += (idx == k) ? 1.f : 0.f;  // static indexing (no scratch)
        }
    }
    // wave reduce (64-wide), then LDS atomic combine across the 4 waves
#define WRED(v) { v += __shfl_down(v,32); v += __shfl_down(v,16); v += __shfl_down(v,8); \
                  v += __shfl_down(v,4);  v += __shfl_down(v,2);  v += __shfl_down(v,1); }
#pragma unroll
    for (int k = 0; k < NATTR; ++k) { WRED(a0[k]); WRED(a1[k]); WRED(pc[k]); }
    WRED(c0); WRED(c1);
#undef WRED
    __shared__ float acc[56];
    if (threadIdx.x < 56) acc[threadIdx.x] = 0.f;
    __syncthreads();
    if ((threadIdx.x & 63) == 0) {
#pragma unroll
        for (int k = 0; k < NATTR; ++k) {
            atomicAdd(&acc[k], a0[k]);
            atomicAdd(&acc[NATTR + k], a1[k]);
            atomicAdd(&acc[2 * NATTR + k], pc[k]);
        }
        atomicAdd(&acc[51], c0);
        atomicAdd(&acc[52], c1);
    }
    __syncthreads();
    if (threadIdx.x < 56) segdata[(size_t)g * 64 + threadIdx.x] = acc[threadIdx.x];
}

// ---------------- k2: pooled[g,:] = (sum_seg x + seg emb contribution) / max(cnt,1) ----------------
// One block per segment; 256 threads x float4 = all 1024 columns. THE 1 GiB reader.
__launch_bounds__(256)
__global__ void k_pool(const float4* __restrict__ x4,
                       const float4* __restrict__ netW4, const float4* __restrict__ netb4,
                       const float4* __restrict__ devW4, const float4* __restrict__ devb4,
                       const float4* __restrict__ pinE4,
                       const int* __restrict__ seg_start, const float* __restrict__ segdata,
                       float4* __restrict__ pooled4) {
    int g = blockIdx.x;
    int s = seg_start[g], e = seg_start[g + 1];
    int t = threadIdx.x;
    __shared__ float sd[53];
    if (t < 53) sd[t] = segdata[(size_t)g * 64 + t];
    __syncthreads();
    int n = e - s;
    const float4* p = x4 + (size_t)s * 256 + t;
    float4 A = f4zero(), B = f4zero(), C = f4zero(), D = f4zero();
    int i = 0;
    for (; i + 4 <= n; i += 4) {
        float4 v0 = p[0];
        float4 v1 = p[256];
        float4 v2 = p[512];
        float4 v3 = p[768];
        p += 1024;
        A = f4add(A, v0); B = f4add(B, v1); C = f4add(C, v2); D = f4add(D, v3);
    }
    for (; i < n; ++i) { A = f4add(A, p[0]); p += 256; }
    float4 acc = f4add(f4add(A, B), f4add(C, D));

    float c0 = sd[51], c1 = sd[52];
    float4 nb = netb4[t], db = devb4[t];
    float4 emb; emb.x = c0*nb.x + c1*db.x; emb.y = c0*nb.y + c1*db.y;
    emb.z = c0*nb.z + c1*db.z; emb.w = c0*nb.w + c1*db.w;
#pragma unroll
    for (int k = 0; k < NATTR; ++k) {
        emb = f4fma(sd[k],            netW4[k * 256 + t], emb);
        emb = f4fma(sd[NATTR + k],    devW4[k * 256 + t], emb);
        emb = f4fma(sd[2*NATTR + k],  pinE4[k * 256 + t], emb);
    }
    float inv = 1.f / fmaxf((float)n, 1.f);
    float4 o;
    o.x = (acc.x + emb.x) * inv; o.y = (acc.y + emb.y) * inv;
    o.z = (acc.z + emb.z) * inv; o.w = (acc.w + emb.w) * inv;
    pooled4[(size_t)g * 256 + t] = o;
}

// ---------------- k3: h0 = relu(pooled @ fc0_W + b); accumulate bn0 col sum/sumsq ----------------
// bn0s: [0..511]=sum, [512..1023]=sumsq
__launch_bounds__(256)
__global__ void k_gemm0(const float* __restrict__ pooled, const float* __restrict__ W,
                        const float* __restrict__ bias, float* __restrict__ h0,
                        float* __restrict__ bn0s) {
    int r0 = blockIdx.x * 4;
    __shared__ float A[4 * 1024];
    const float4* P4 = (const float4*)(pooled + (size_t)r0 * 1024);
    float4* A4 = (float4*)A;
    for (int j = threadIdx.x; j < 1024; j += 256) A4[j] = P4[j];
    __syncthreads();
    int c = threadIdx.x;
    float acc[4][2] = {{0.f,0.f},{0.f,0.f},{0.f,0.f},{0.f,0.f}};
#pragma unroll 4
    for (int k = 0; k < 1024; ++k) {
        float w0 = W[k * 512 + c];
        float w1 = W[k * 512 + c + 256];
#pragma unroll
        for (int r = 0; r < 4; ++r) {
            float a = A[r * 1024 + k];
            acc[r][0] = fmaf(a, w0, acc[r][0]);
            acc[r][1] = fmaf(a, w1, acc[r][1]);
        }
    }
    float b0 = bias[c], b1 = bias[c + 256];
    float s0 = 0.f, q0 = 0.f, s1 = 0.f, q1 = 0.f;
#pragma unroll
    for (int r = 0; r < 4; ++r) {
        float h_0 = fmaxf(acc[r][0] + b0, 0.f);
        float h_1 = fmaxf(acc[r][1] + b1, 0.f);
        h0[(size_t)(r0 + r) * 512 + c]       = h_0;
        h0[(size_t)(r0 + r) * 512 + c + 256] = h_1;
        s0 += h_0; q0 += h_0 * h_0;
        s1 += h_1; q1 += h_1 * h_1;
    }
    atomicAdd(&bn0s[c], s0);        atomicAdd(&bn0s[512 + c], q0);
    atomicAdd(&bn0s[c + 256], s1);  atomicAdd(&bn0s[512 + c + 256], q1);
}

// ---------------- k4: h1 = relu(bn0(h0) @ fc1_W + b); accumulate bn1 stats ----------------
__launch_bounds__(256)
__global__ void k_gemm1(const float* __restrict__ h0, const float* __restrict__ bn0s,
                        const float* __restrict__ g0, const float* __restrict__ b0v,
                        const float* __restrict__ W, const float* __restrict__ bias,
                        float* __restrict__ h1, float* __restrict__ bn1s) {
    int r0 = blockIdx.x * 4;
    __shared__ float A[4 * 512];
    const float invG = 1.f / (float)G_SEG;
    for (int j = threadIdx.x; j < 2048; j += 256) {
        int k = j & 511;
        float v  = h0[(size_t)r0 * 512 + j];
        float mu = bn0s[k] * invG;
        float var = bn0s[512 + k] * invG - mu * mu;
        float istd = rsqrtf(var + EPS_BN);
        A[j] = (v - mu) * istd * g0[k] + b0v[k];
    }
    __syncthreads();
    int c = threadIdx.x;
    float acc[4] = {0.f, 0.f, 0.f, 0.f};
#pragma unroll 4
    for (int k = 0; k < 512; ++k) {
        float w = W[k * 256 + c];
#pragma unroll
        for (int r = 0; r < 4; ++r) acc[r] = fmaf(A[r * 512 + k], w, acc[r]);
    }
    float bb = bias[c];
    float s = 0.f, q = 0.f;
#pragma unroll
    for (int r = 0; r < 4; ++r) {
        float h = fmaxf(acc[r] + bb, 0.f);
        h1[(size_t)(r0 + r) * 256 + c] = h;
        s += h; q += h * h;
    }
    atomicAdd(&bn1s[c], s);
    atomicAdd(&bn1s[256 + c], q);
}

// ---------------- k5: pred = bn1(h1) @ fc2_W + b; out[0..G)=pred, out[G..2G)=y_reg ----------------
__launch_bounds__(64)
__global__ void k_out(const float* __restrict__ h1, const float* __restrict__ bn1s,
                      const float* __restrict__ g1, const float* __restrict__ b1v,
                      const float* __restrict__ W2, const float* __restrict__ b2,
                      const float* __restrict__ yreg, float* __restrict__ out) {
    int r = blockIdx.x;
    int l = threadIdx.x;
    const float invG = 1.f / (float)G_SEG;
    float sum = 0.f;
#pragma unroll
    for (int j = 0; j < 4; ++j) {
        int k = l + 64 * j;
        float v  = h1[(size_t)r * 256 + k];
        float mu = bn1s[k] * invG;
        float var = bn1s[256 + k] * invG - mu * mu;
        float istd = rsqrtf(var + EPS_BN);
        float a = (v - mu) * istd * g1[k] + b1v[k];
        sum = fmaf(a, W2[k], sum);
    }
    sum += __shfl_down(sum, 32); sum += __shfl_down(sum, 16); sum += __shfl_down(sum, 8);
    sum += __shfl_down(sum, 4);  sum += __shfl_down(sum, 2);  sum += __shfl_down(sum, 1);
    if (l == 0) {
        out[r]         = sum + b2[0];
        out[G_SEG + r] = yreg[r];
    }
}

extern "C" void kernel_launch(void* const* d_in, const int* in_sizes, int n_in,
                              void* d_out, int out_size, void* d_ws, size_t ws_size,
                              hipStream_t stream) {
    const float* x     = (const float*)d_in[0];
    const float* attr  = (const float*)d_in[1];
    const int*   ntype = (const int*)d_in[2];
    const int*   batch = (const int*)d_in[3];
    const float* yreg  = (const float*)d_in[4];
    const float* netW  = (const float*)d_in[5];
    const float* netb  = (const float*)d_in[6];
    const float* devW  = (const float*)d_in[7];
    const float* devb  = (const float*)d_in[8];
    const float* pinE  = (const float*)d_in[9];
    const float* fc0W  = (const float*)d_in[10];
    const float* fc0b  = (const float*)d_in[11];
    const float* fc1W  = (const float*)d_in[12];
    const float* fc1b  = (const float*)d_in[13];
    const float* fc2W  = (const float*)d_in[14];
    const float* fc2b  = (const float*)d_in[15];
    const float* bn0g  = (const float*)d_in[16];
    const float* bn0b  = (const float*)d_in[17];
    const float* bn1g  = (const float*)d_in[18];
    const float* bn1b  = (const float*)d_in[19];
    float* out = (float*)d_out;

    char* ws = (char*)d_ws;
    int*   seg_start = (int*)ws;                              // 1025 ints (pad to 8 KiB)
    float* segdata   = (float*)(ws + 8192);                   // 1024*64 floats = 256 KiB
    float* pooled    = (float*)(ws + 8192 + 262144);          // 1024*1024 f = 4 MiB
    float* h0        = pooled + (size_t)G_SEG * DIM;          // 1024*512 f = 2 MiB
    float* h1        = h0 + (size_t)G_SEG * 512;              // 1024*256 f = 1 MiB
    float* bn0s      = h1 + (size_t)G_SEG * 256;              // 1024 f
    float* bn1s      = bn0s + 1024;                           // 512 f

    hipMemsetAsync(bn0s, 0, (1024 + 512) * sizeof(float), stream);

    k_seg_bounds<<<5, 256, 0, stream>>>(batch, seg_start);
    k_attr_sums<<<G_SEG, 256, 0, stream>>>(attr, ntype, seg_start, segdata);
    k_pool<<<G_SEG, 256, 0, stream>>>((const float4*)x,
                                      (const float4*)netW, (const float4*)netb,
                                      (const float4*)devW, (const float4*)devb,
                                      (const float4*)pinE,
                                      seg_start, segdata, (float4*)pooled);
    k_gemm0<<<G_SEG / 4, 256, 0, stream>>>(pooled, fc0W, fc0b, h0, bn0s);
    k_gemm1<<<G_SEG / 4, 256, 0, stream>>>(h0, bn0s, bn0g, bn0b, fc1W, fc1b, h1, bn1s);
    k_out<<<G_SEG, 64, 0, stream>>>(h1, bn1s, bn1g, bn1b, fc2W, fc2b, yreg, out);
}